// Round 6
// baseline (220.348 us; speedup 1.0000x reference)
//
#include <hip/hip_runtime.h>

#define BB 64
#define SC 640
#define SN 128
#define DD 768
#define CODE_DEF 254
#define NL_DEF 126

typedef short bf16x8 __attribute__((ext_vector_type(8)));
typedef float f32x4 __attribute__((ext_vector_type(4)));

__device__ __forceinline__ unsigned short f2bf(float f) {
  unsigned u = __float_as_uint(f);
  u += 0x7fffu + ((u >> 16) & 1u);  // round-to-nearest-even
  return (unsigned short)(u >> 16);
}

// ---------------- K0: per-batch prep -----------------------------------------
__global__ __launch_bounds__(64) void k0_prep(
    const int* __restrict__ code_ids, const int* __restrict__ nl_ids,
    const int* __restrict__ pos, const unsigned* __restrict__ attn_u32,
    int* __restrict__ nn, int* __restrict__ node_idx,
    int* __restrict__ len_code, int* __restrict__ len_nl,
    int* __restrict__ flag) {
  int b = blockIdx.x;
  int lane = threadIdx.x;  // 0..63
  int first = CODE_DEF;
  for (int c = 0; c < SC; c += 64) {
    bool is2 = code_ids[b * SC + c + lane] == 2;
    unsigned long long m = __ballot(is2);
    if (m) { first = c + __builtin_ctzll(m); break; }
  }
  int firstn = NL_DEF;
  for (int c = 0; c < SN; c += 64) {
    bool is2 = nl_ids[b * SN + c + lane] == 2;
    unsigned long long m = __ballot(is2);
    if (m) { firstn = c + __builtin_ctzll(m); break; }
  }
  int base = 0;
  for (int c = 0; c < SC; c += 64) {
    bool isn = pos[b * SC + c + lane] == 0;
    unsigned long long m = __ballot(isn);
    int pre = __popcll(m & ((1ull << lane) - 1ull));
    if (isn) node_idx[b * SC + base + pre] = c + lane;
    base += __popcll(m);
  }
  if (lane == 0) { nn[b] = base; len_code[b] = first; len_nl[b] = firstn; }
  if (b == 0) {
    int bad = 0;
    for (int i = lane; i < 1024; i += 64)
      if (attn_u32[i] > 1u) bad = 1;
    unsigned long long m = __ballot(bad);
    if (lane == 0) flag[0] = (m != 0ull) ? 1 : 0;
  }
}

// ---------------- K0b: pack (attn && token_mask) bits per node row -----------
__global__ __launch_bounds__(256) void k0b_mask(
    const int* __restrict__ attn, const int* __restrict__ pos,
    const int* __restrict__ nn, const int* __restrict__ node_idx,
    const int* __restrict__ flag,
    unsigned long long* __restrict__ mbits64, float* __restrict__ counts) {
  int id = blockIdx.x;
  int b = id & 63, g = id >> 6;  // g 0..15
  int w = threadIdx.x >> 6, lane = threadIdx.x & 63;
  int count = nn[b];
  int isu8 = flag[0];
  for (int rr = 0; rr < 4; ++rr) {
    int slot = g * 16 + w * 4 + rr;
    long obase = ((long)b * 256 + slot) * 10;
    if (slot >= count) {
      if (lane < 10) mbits64[obase + lane] = 0ull;
      if (lane == 0) counts[b * 256 + slot] = 0.f;
      continue;
    }
    int nrow = node_idx[b * SC + slot];
    int tot = 0;
    for (int k = 0; k < 10; ++k) {
      int t = k * 64 + lane;
      bool tk = pos[b * SC + t] >= 2;
      bool av;
      if (isu8)
        av = ((const unsigned char*)attn)[((long)b * SC + nrow) * SC + t] != 0;
      else
        av = attn[((long)b * SC + nrow) * SC + t] != 0;
      unsigned long long m = __ballot(av && tk);
      if (lane == 0) mbits64[obase + k] = m;
      tot += __popcll(m);
    }
    if (lane == 0) counts[b * 256 + slot] = (float)tot;
  }
}

// ---------------- kT: gather Wemb -> bf16 transposed blob ---------------------
// blob layout: [b][c(10)][d(768)][t(64)] bf16 (t contiguous).
#define TPAD 132
__global__ __launch_bounds__(256) void kT_blob(
    const int* __restrict__ code_ids, const float* __restrict__ Wemb,
    unsigned short* __restrict__ blob) {
  __shared__ float T[64][TPAD];
  __shared__ int cid_l[64];
  int id = blockIdx.x;
  int b = id & 63, c = id >> 6;  // c 0..9
  int tid = threadIdx.x;
  if (tid < 64) cid_l[tid] = code_ids[b * SC + c * 64 + tid];
  __syncthreads();
  unsigned short* ob = blob + (long)(b * 10 + c) * (DD * 64);
  for (int p = 0; p < 6; ++p) {
    int col4 = (tid & 31) * 4;
#pragma unroll
    for (int it = 0; it < 8; ++it) {
      int row = it * 8 + (tid >> 5);  // 0..63; 32 lanes read 512B of one row
      f32x4 v = *(const f32x4*)(Wemb + (long)cid_l[row] * DD + p * 128 + col4);
      *(f32x4*)(&T[row][col4]) = v;
    }
    __syncthreads();
#pragma unroll
    for (int it2 = 0; it2 < 4; ++it2) {
      int task = tid + 256 * it2;  // 1024: 128 d x 8 t-groups
      int dl = task >> 3, tg = task & 7;
      bf16x8 u;
#pragma unroll
      for (int j = 0; j < 8; ++j) u[j] = (short)f2bf(T[tg * 8 + j][dl]);
      *(bf16x8*)(ob + (long)(p * 128 + dl) * 64 + tg * 8) = u;  // coalesced
    }
    __syncthreads();
  }
}

// ---------------- K2: node-avg GEMM from blob (k5-style linear staging) ------
// As: mask bf16 [128 node][64 t]; Bs: embT bf16 [128 d][64 t];
// both XOR-swizzled elem^=(row&7)<<3.
__global__ __launch_bounds__(256) void k2_mfma(
    const unsigned* __restrict__ mbits, const float* __restrict__ counts,
    const int* __restrict__ nn, const int* __restrict__ node_idx,
    const unsigned short* __restrict__ blob, float* __restrict__ codeh) {
  __shared__ unsigned short As[128 * 64];
  __shared__ unsigned short Bs[128 * 64];
  __shared__ int rowsidx[128];
  int id = blockIdx.x;
  int b = id & 63;   // same-b -> same XCD (stride 64)
  int g = id >> 6;   // 0..11
  int ntile = g / 6, dtile = g % 6;
  int count = nn[b];
  if (ntile * 128 >= count) return;
  int tid = threadIdx.x;
  if (tid < 128) {
    int slot = ntile * 128 + tid;
    rowsidx[tid] = (slot < count) ? node_idx[b * SC + slot] : -1;
  }
  const int lane = tid & 63, w = tid >> 6, wm = w >> 1, wn = w & 1;

  f32x4 acc[4][4];
#pragma unroll
  for (int m = 0; m < 4; ++m)
#pragma unroll
    for (int n = 0; n < 4; ++n) acc[m][n] = (f32x4){0.f, 0.f, 0.f, 0.f};

  const int r_ = tid >> 1, h_ = tid & 1;
  const unsigned* mrow = mbits + ((long)b * 256 + ntile * 128 + r_) * 20;

  for (int c = 0; c < 10; ++c) {
    const unsigned short* src =
        blob + (long)(b * 10 + c) * (DD * 64) + dtile * (128 * 64);
    unsigned bitsv = mrow[c * 2 + h_];
    // B stage: 16KB linear copy, 4 iters x 16B/thread
#pragma unroll
    for (int it = 0; it < 4; ++it) {
      int task = tid + 256 * it;
      int drow = task >> 3, tg = task & 7;
      bf16x8 v = *(const bf16x8*)(src + drow * 64 + tg * 8);
      *(bf16x8*)(&Bs[drow * 64 + ((tg * 8) ^ ((drow & 7) << 3))]) = v;
    }
    // A stage: expand mask bits
#pragma unroll
    for (int gg = 0; gg < 4; ++gg) {
      int tl = h_ * 32 + gg * 8;
      bf16x8 u;
#pragma unroll
      for (int j = 0; j < 8; ++j)
        u[j] = ((bitsv >> (gg * 8 + j)) & 1u) ? (short)0x3F80 : (short)0;
      *(bf16x8*)(&As[r_ * 64 + (tl ^ ((r_ & 7) << 3))]) = u;
    }
    __syncthreads();
#pragma unroll
    for (int ks = 0; ks < 2; ++ks) {
      int kb = ks * 32 + (lane >> 4) * 8;
      bf16x8 af[4], bfv[4];
#pragma unroll
      for (int m = 0; m < 4; ++m) {
        int rr = wm * 64 + m * 16 + (lane & 15);
        af[m] = *(const bf16x8*)(&As[rr * 64 + (kb ^ ((rr & 7) << 3))]);
      }
#pragma unroll
      for (int n = 0; n < 4; ++n) {
        int cc = wn * 64 + n * 16 + (lane & 15);
        bfv[n] = *(const bf16x8*)(&Bs[cc * 64 + (kb ^ ((cc & 7) << 3))]);
      }
#pragma unroll
      for (int m = 0; m < 4; ++m)
#pragma unroll
        for (int n = 0; n < 4; ++n)
          acc[m][n] = __builtin_amdgcn_mfma_f32_16x16x32_bf16(af[m], bfv[n],
                                                              acc[m][n], 0, 0, 0);
    }
    __syncthreads();
  }

  // epilogue: divide by count, scatter raw avg to node rows
  float* outb = codeh + (long)b * SC * DD + dtile * 128 + wn * 64;
#pragma unroll
  for (int m = 0; m < 4; ++m) {
    int row0 = wm * 64 + m * 16 + ((lane >> 4) << 2);
#pragma unroll
    for (int rr2 = 0; rr2 < 4; ++rr2) {
      int slotr = row0 + rr2;
      int nr = rowsidx[slotr];
      if (nr < 0) continue;
      float cnt = counts[b * 256 + ntile * 128 + slotr];
      float inv = (cnt > 0.f) ? 1.f / cnt : 0.f;
      float* orow = outb + (long)nr * DD;
#pragma unroll
      for (int n = 0; n < 4; ++n)
        orow[n * 16 + (lane & 15)] = acc[m][n][rr2] * inv;
    }
  }
}

// ---------------- K3: fused gather + l2norm + role + probs (wave/row) --------
__global__ __launch_bounds__(256) void k3_fused(
    const int* __restrict__ code_ids, const int* __restrict__ pos,
    const float* __restrict__ Wemb, float* __restrict__ codeh,
    const int* __restrict__ roles, const float* __restrict__ role_table,
    const float* __restrict__ w_code, const float* __restrict__ b_code,
    const int* __restrict__ len_code, float* __restrict__ code_probs) {
  int w = threadIdx.x >> 6, lane = threadIdx.x & 63;
  long row = (long)blockIdx.x * 4 + w;
  int b = (int)(row / SC), s = (int)(row % SC);
  float* rp = codeh + row * DD;
  const float* src =
      (pos[row] == 0) ? rp : (Wemb + (long)code_ids[row] * DD);
  f32x4 x[3];
#pragma unroll
  for (int j = 0; j < 3; ++j)
    x[j] = *(const f32x4*)(src + lane * 4 + j * 256);
  float ss = 0.f;
#pragma unroll
  for (int j = 0; j < 3; ++j)
#pragma unroll
    for (int e = 0; e < 4; ++e) ss += x[j][e] * x[j][e];
#pragma unroll
  for (int o = 32; o > 0; o >>= 1) ss += __shfl_xor(ss, o, 64);
  float inv = 1.f / fmaxf(sqrtf(ss), 1e-12f);
  const float* rt = role_table + (long)roles[row] * DD;
  float dot = 0.f;
#pragma unroll
  for (int j = 0; j < 3; ++j) {
    f32x4 r = *(const f32x4*)(rt + lane * 4 + j * 256);
    f32x4 wc = *(const f32x4*)(w_code + lane * 4 + j * 256);
    f32x4 y;
#pragma unroll
    for (int e = 0; e < 4; ++e) {
      y[e] = x[j][e] * inv;
      dot += (y[e] + r[e]) * wc[e];
    }
    *(f32x4*)(rp + lane * 4 + j * 256) = y;
  }
#pragma unroll
  for (int o = 32; o > 0; o >>= 1) dot += __shfl_xor(dot, o, 64);
  if (lane == 0) {
    float p = 1.f / (1.f + expf(-(dot + b_code[0])));
    code_probs[row] = (s < len_code[b]) ? p : 0.f;
  }
}

// ---------------- K4: nl branch (wave/row) ------------------------------------
__global__ __launch_bounds__(256) void k4_nl(
    const int* __restrict__ ids, const float* __restrict__ Wemb,
    const float* __restrict__ w_nl, const float* __restrict__ b_nl,
    const int* __restrict__ len_nl, float* __restrict__ nlh,
    float* __restrict__ nl_probs) {
  int w = threadIdx.x >> 6, lane = threadIdx.x & 63;
  long row = (long)blockIdx.x * 4 + w;
  int b = (int)(row / SN), s = (int)(row % SN);
  const float* src = Wemb + (long)ids[row] * DD;
  f32x4 x[3];
#pragma unroll
  for (int j = 0; j < 3; ++j)
    x[j] = *(const f32x4*)(src + lane * 4 + j * 256);
  float ss = 0.f;
#pragma unroll
  for (int j = 0; j < 3; ++j)
#pragma unroll
    for (int e = 0; e < 4; ++e) ss += x[j][e] * x[j][e];
#pragma unroll
  for (int o = 32; o > 0; o >>= 1) ss += __shfl_xor(ss, o, 64);
  float inv = 1.f / fmaxf(sqrtf(ss), 1e-12f);
  float* o = nlh + row * DD;
  float dot = 0.f;
#pragma unroll
  for (int j = 0; j < 3; ++j) {
    f32x4 wn = *(const f32x4*)(w_nl + lane * 4 + j * 256);
    f32x4 y;
#pragma unroll
    for (int e = 0; e < 4; ++e) {
      y[e] = x[j][e] * inv;
      dot += y[e] * wn[e];
    }
    *(f32x4*)(o + lane * 4 + j * 256) = y;
  }
#pragma unroll
  for (int of = 32; of > 0; of >>= 1) dot += __shfl_xor(dot, of, 64);
  if (lane == 0) {
    float p = 1.f / (1.f + expf(-(dot + b_nl[0])));
    nl_probs[row] = (s < len_nl[b]) ? p : 0.f;
  }
}

// ---------------- K5: sim via bf16 MFMA, 64x128 tiles (640 blocks) -----------
__global__ __launch_bounds__(256) void k5_mfma(const float* __restrict__ nlh,
                                               const float* __restrict__ codeh,
                                               float* __restrict__ sim) {
  __shared__ unsigned short As[64 * 64];
  __shared__ unsigned short Bs[128 * 64];
  int id = blockIdx.x;
  int b = id & 63;
  int r = id >> 6;             // 0..9
  int nt = r % 2, ct = r / 2;  // nl half, code 128-tile
  int tid = threadIdx.x;
  int lane = tid & 63;
  int w = tid >> 6;
  int wm = w >> 1, wn = w & 1;  // wave: 32 nl x 64 code

  f32x4 acc[2][4];
#pragma unroll
  for (int m = 0; m < 2; ++m)
#pragma unroll
    for (int n = 0; n < 4; ++n) acc[m][n] = (f32x4){0.f, 0.f, 0.f, 0.f};

  const float* Ag = nlh + ((long)b * SN + nt * 64) * DD;
  const float* Bg = codeh + ((long)b * SC + ct * 128) * DD;

  for (int c = 0; c < DD / 64; ++c) {
#pragma unroll
    for (int it = 0; it < 4; ++it) {
      int i = tid + 256 * it;  // 0..1023
      int row = i >> 4, k0 = (i & 15) * 4;
      float4 va = *(const float4*)(Ag + (long)row * DD + c * 64 + k0);
      ushort4 ua = {f2bf(va.x), f2bf(va.y), f2bf(va.z), f2bf(va.w)};
      *(ushort4*)(&As[row * 64 + (k0 ^ ((row & 7) << 3))]) = ua;
    }
#pragma unroll
    for (int it = 0; it < 8; ++it) {
      int i = tid + 256 * it;  // 0..2047
      int row = i >> 4, k0 = (i & 15) * 4;
      float4 vb = *(const float4*)(Bg + (long)row * DD + c * 64 + k0);
      ushort4 ub = {f2bf(vb.x), f2bf(vb.y), f2bf(vb.z), f2bf(vb.w)};
      *(ushort4*)(&Bs[row * 64 + (k0 ^ ((row & 7) << 3))]) = ub;
    }
    __syncthreads();
#pragma unroll
    for (int ks = 0; ks < 2; ++ks) {
      int kb = ks * 32 + (lane >> 4) * 8;
      bf16x8 af[2], bfr[4];
#pragma unroll
      for (int m = 0; m < 2; ++m) {
        int rr = wm * 32 + m * 16 + (lane & 15);
        af[m] = *(const bf16x8*)(&As[rr * 64 + (kb ^ ((rr & 7) << 3))]);
      }
#pragma unroll
      for (int n = 0; n < 4; ++n) {
        int rr = wn * 64 + n * 16 + (lane & 15);
        bfr[n] = *(const bf16x8*)(&Bs[rr * 64 + (kb ^ ((rr & 7) << 3))]);
      }
#pragma unroll
      for (int m = 0; m < 2; ++m)
#pragma unroll
        for (int n = 0; n < 4; ++n)
          acc[m][n] = __builtin_amdgcn_mfma_f32_16x16x32_bf16(
              af[m], bfr[n], acc[m][n], 0, 0, 0);
    }
    __syncthreads();
  }
  long ob = ((long)b * SN + nt * 64) * SC + ct * 128;
#pragma unroll
  for (int m = 0; m < 2; ++m) {
    int row0 = wm * 32 + m * 16 + ((lane >> 4) << 2);
#pragma unroll
    for (int n = 0; n < 4; ++n) {
      int col = wn * 64 + n * 16 + (lane & 15);
#pragma unroll
      for (int rr = 0; rr < 4; ++rr)
        sim[ob + (long)(row0 + rr) * SC + col] = acc[m][n][rr];
    }
  }
}

// ---------------- launcher ---------------------------------------------------
extern "C" void kernel_launch(void* const* d_in, const int* in_sizes, int n_in,
                              void* d_out, int out_size, void* d_ws,
                              size_t ws_size, hipStream_t stream) {
  const int* code_ids = (const int*)d_in[0];
  const int* attn = (const int*)d_in[1];
  const int* pos = (const int*)d_in[2];
  const int* nl_ids = (const int*)d_in[3];
  const int* roles = (const int*)d_in[4];
  const float* Wemb = (const float*)d_in[5];
  const float* role_table = (const float*)d_in[6];
  const float* w_code = (const float*)d_in[7];
  const float* b_code = (const float*)d_in[8];
  const float* w_nl = (const float*)d_in[9];
  const float* b_nl = (const float*)d_in[10];

  float* out = (float*)d_out;
  float* codeh = out;                  // 64*640*768
  float* code_probs = out + 31457280;  // 64*640
  float* nlh = out + 31498240;         // 64*128*768
  float* nl_probs = out + 37789696;    // 64*128
  float* sim = out + 37797888;         // 64*128*640

  int* wsi = (int*)d_ws;
  int* nn = wsi;                        // 64
  int* node_idx = wsi + 64;             // 64*640
  int* len_code = node_idx + BB * SC;   // 64
  int* len_nl = len_code + 64;          // 64
  int* flag = len_nl + 64;              // 1
  unsigned* mbits = (unsigned*)(wsi + 49152);       // 64*256*20 u32
  float* counts = (float*)(wsi + 49152 + 327680);   // 64*256
  unsigned short* blob =
      (unsigned short*)((char*)d_ws + (8u << 20));  // 64*10*768*64 bf16 = 63MB

  k0_prep<<<BB, 64, 0, stream>>>(code_ids, nl_ids, pos, (const unsigned*)attn,
                                 nn, node_idx, len_code, len_nl, flag);
  k0b_mask<<<BB * 16, 256, 0, stream>>>(attn, pos, nn, node_idx, flag,
                                        (unsigned long long*)mbits, counts);
  kT_blob<<<BB * 10, 256, 0, stream>>>(code_ids, Wemb, blob);
  k4_nl<<<BB * SN / 4, 256, 0, stream>>>(nl_ids, Wemb, w_nl, b_nl, len_nl, nlh,
                                         nl_probs);
  k2_mfma<<<BB * 12, 256, 0, stream>>>(mbits, counts, nn, node_idx, blob,
                                       codeh);
  k3_fused<<<BB * SC / 4, 256, 0, stream>>>(code_ids, pos, Wemb, codeh, roles,
                                            role_table, w_code, b_code,
                                            len_code, code_probs);
  k5_mfma<<<BB * 10, 256, 0, stream>>>(nlh, codeh, sim);
}